// Round 3
// baseline (242.571 us; speedup 1.0000x reference)
//
#include <hip/hip_runtime.h>

#define L_SEQ 1024
#define EMB 1024
#define NH 16
#define HD 64

typedef _Float16 half8 __attribute__((ext_vector_type(8)));
typedef _Float16 half4v __attribute__((ext_vector_type(4)));
typedef float f32x4 __attribute__((ext_vector_type(4)));
typedef float fvec4 __attribute__((ext_vector_type(4)));
typedef unsigned int u32;
typedef unsigned long long u64;

constexpr float C2 = 0.045084220027780106f;   // SCALE * log2(e)  (folded into Q)
constexpr float F2 = -45.08422002778011f;     // MASK_FILL * SCALE * log2(e)

constexpr int PP = 72;   // P_lds / cvt pitch (144 B rows: 16B-aligned, 2-way alias only)

__device__ __forceinline__ void async16(const void* g, void* l) {
    __builtin_amdgcn_global_load_lds((const __attribute__((address_space(1))) u32*)g,
                                     (__attribute__((address_space(3))) u32*)l, 16, 0, 0);
}

// ---------------------------------------------------------------------------
// Prepass: pack attn_mask into bitmask via wave ballot
// ---------------------------------------------------------------------------
__global__ void pack_mask_kernel(const int* __restrict__ am, u32* __restrict__ bits) {
    const int i = blockIdx.x * 256 + threadIdx.x;
    const int lane = threadIdx.x & 63;
    u64 b = __ballot(am[i] != 0);
    if (lane == 0)       bits[i >> 5] = (u32)b;
    else if (lane == 32) bits[i >> 5] = (u32)(b >> 32);
}

// ---------------------------------------------------------------------------
// Prepass: cmb[n][q][w] = attn_bits[q][w] & pad_bits[n][w]   (grid 128 x 256)
// ---------------------------------------------------------------------------
__global__ void combine_mask_kernel(const u32* __restrict__ abits,
                                    const u32* __restrict__ pbits,
                                    u32* __restrict__ cmb) {
    const int tid = threadIdx.x;
    const int w = tid & 31, qq = tid >> 5;
    const int q = blockIdx.x * 8 + qq;
    const u32 a = abits[q * 32 + w];
#pragma unroll
    for (int n = 0; n < 8; ++n)
        cmb[((size_t)(n * L_SEQ) + q) * 32 + w] = a & pbits[n * 32 + w];
}

// ---------------------------------------------------------------------------
// Prepass: fc_w fp32 -> f16
// ---------------------------------------------------------------------------
__global__ void convert_w_kernel(const float* __restrict__ w, _Float16* __restrict__ o) {
    size_t i = ((size_t)blockIdx.x * blockDim.x + threadIdx.x) * 4;
    fvec4 v = *(const fvec4*)(w + i);
    half4v h;
#pragma unroll
    for (int j = 0; j < 4; ++j) h[j] = (_Float16)v[j];
    *(half4v*)(o + i) = h;
}

// ---------------------------------------------------------------------------
// Prepass: K -> f16 head-blocked (nh,k,d); V -> f16 transposed (nh,d,k);
// also packs pad bits (blocks with h==0). grid (16 kt, 16 h, 8 n), 256 thr.
// ---------------------------------------------------------------------------
__global__ __launch_bounds__(256) void cvt_kv_kernel(
    const float* __restrict__ keys, const float* __restrict__ values,
    const int* __restrict__ pad_mask,
    _Float16* __restrict__ K16, _Float16* __restrict__ Vt16, u32* __restrict__ pbits)
{
    __shared__ __align__(16) _Float16 Vt[64 * PP];
    const int tid = threadIdx.x;
    const int kt = blockIdx.x, h = blockIdx.y, n = blockIdx.z;
    const int kbase = kt * 64;
    const int r = tid >> 2, c0 = (tid & 3) * 16;
    const int nh = n * NH + h;

    {   // K: head-blocked + f16
        const float* src = keys + ((size_t)(n * L_SEQ + kbase + r)) * EMB + h * HD + c0;
        fvec4 a0 = *(const fvec4*)(src),     a1 = *(const fvec4*)(src + 4);
        fvec4 a2 = *(const fvec4*)(src + 8), a3 = *(const fvec4*)(src + 12);
        half8 o0, o1;
#pragma unroll
        for (int j = 0; j < 4; ++j) {
            o0[j] = (_Float16)a0[j]; o0[j + 4] = (_Float16)a1[j];
            o1[j] = (_Float16)a2[j]; o1[j + 4] = (_Float16)a3[j];
        }
        _Float16* dst = K16 + ((size_t)nh * L_SEQ + kbase + r) * HD + c0;
        *(half8*)dst = o0; *(half8*)(dst + 8) = o1;
    }
    {   // V transpose via LDS
        const float* src = values + ((size_t)(n * L_SEQ + kbase + r)) * EMB + h * HD + c0;
        fvec4 vv[4];
        vv[0] = *(const fvec4*)(src);     vv[1] = *(const fvec4*)(src + 4);
        vv[2] = *(const fvec4*)(src + 8); vv[3] = *(const fvec4*)(src + 12);
#pragma unroll
        for (int i = 0; i < 16; ++i)
            Vt[(c0 + i) * PP + r] = (_Float16)vv[i >> 2][i & 3];
    }
    if (blockIdx.y == 0 && tid < 64) {      // pad bits (wave 0 whole -> ballot ok)
        u64 b = __ballot(pad_mask[(size_t)n * L_SEQ + kbase + tid] != 0);
        if (tid == 0)       pbits[n * 32 + kt * 2]     = (u32)b;
        else if (tid == 32) pbits[n * 32 + kt * 2 + 1] = (u32)(b >> 32);
    }
    __syncthreads();
    {
        const int d = tid >> 2, k0 = (tid & 3) * 16;
        half8 v0 = *(const half8*)(&Vt[d * PP + k0]);
        half8 v1 = *(const half8*)(&Vt[d * PP + k0 + 8]);
        _Float16* dst = Vt16 + ((size_t)nh * HD + d) * L_SEQ + kbase + k0;
        *(half8*)dst = v0; *(half8*)(dst + 8) = v1;
    }
}

// ---------------------------------------------------------------------------
// Fused masked attention, S^T formulation, double-buffered K/V via DMA,
// ONE barrier per K-iteration (DMA overlaps whole compute phase).
// grid 1024 (bid = nh + 128*qt), block 256 (4 waves), qtile=128, ktile=64.
// ---------------------------------------------------------------------------
__global__ __launch_bounds__(256, 3) void attn_kernel(
    const _Float16* __restrict__ K16, const _Float16* __restrict__ Vt16,
    const float* __restrict__ queries, const u32* __restrict__ cmb,
    _Float16* __restrict__ out_f16)
{
    __shared__ __align__(16) _Float16 K_lds[2][64 * 64];   // XOR-swizzled, DMA-staged
    __shared__ __align__(16) _Float16 V_lds[2][64 * 64];
    __shared__ __align__(16) _Float16 P_lds[128 * PP];

    const int tid = threadIdx.x;
    const int lane = tid & 63;
    const int wave = tid >> 6;
    const int l16 = lane & 15;
    const int quad = lane >> 4;
    const int bid = blockIdx.x;
    const int nh = bid & 127, qt = bid >> 7;
    const int n = nh >> 4, h = nh & 15;
    const int qbase = qt * 128;
    const int xr = l16 & 7;

    // --- Q fragments (B operand), pre-scaled by SCALE*log2e
    half8 qf[2][2];
#pragma unroll
    for (int s = 0; s < 2; ++s) {
        const int qrow = qbase + wave * 32 + s * 16 + l16;
        const float* qp = queries + ((size_t)(n * L_SEQ + qrow)) * EMB + h * HD;
#pragma unroll
        for (int t = 0; t < 2; ++t) {
            fvec4 a = *(const fvec4*)(qp + t * 32 + quad * 8);
            fvec4 b = *(const fvec4*)(qp + t * 32 + quad * 8 + 4);
#pragma unroll
            for (int j = 0; j < 4; ++j) {
                qf[s][t][j]     = (_Float16)(a[j] * C2);
                qf[s][t][j + 4] = (_Float16)(b[j] * C2);
            }
        }
    }

    f32x4 Ov[2][4];
#pragma unroll
    for (int s = 0; s < 2; ++s)
#pragma unroll
        for (int dt = 0; dt < 4; ++dt) Ov[s][dt] = (f32x4){0.f, 0.f, 0.f, 0.f};
    float lsum[2] = {0.f, 0.f};

    const _Float16* Kt_base = K16 + (size_t)nh * L_SEQ * HD;
    const _Float16* Vt_base = Vt16 + (size_t)nh * HD * L_SEQ;
    const int gch = (lane & 7) ^ ((lane >> 3) & 7);      // source-side XOR swizzle
    const int drow = (lane >> 3);                        // row-in-group for DMA src
    const u32* mrow0 = cmb + ((size_t)(n * L_SEQ) + qbase + wave * 32 + l16) * 32;
    const u32* mrow1 = mrow0 + 16 * 32;

    // --- prologue: DMA tile 0 into buf 0
#pragma unroll
    for (int s2 = 0; s2 < 2; ++s2) {
        const int row = wave * 16 + s2 * 8 + drow;
        async16(Kt_base + (size_t)row * HD + gch * 8, &K_lds[0][(wave * 16 + s2 * 8) * 64]);
        async16(Vt_base + (size_t)row * L_SEQ + gch * 8, &V_lds[0][(wave * 16 + s2 * 8) * 64]);
    }

    for (int kt = 0; kt < L_SEQ / 64; ++kt) {
        const int cb = kt & 1;
        __syncthreads();   // drains DMA for tile kt (in flight since last iter)

        if (kt < 15) {     // DMA tile kt+1 into other buffer — overlaps compute
            const int kb2 = (kt + 1) * 64;
#pragma unroll
            for (int s2 = 0; s2 < 2; ++s2) {
                const int row = wave * 16 + s2 * 8 + drow;
                async16(Kt_base + (size_t)(kb2 + row) * HD + gch * 8,
                        &K_lds[cb ^ 1][(wave * 16 + s2 * 8) * 64]);
                async16(Vt_base + (size_t)row * L_SEQ + kb2 + gch * 8,
                        &V_lds[cb ^ 1][(wave * 16 + s2 * 8) * 64]);
            }
        }
        const u32 w0a = mrow0[kt * 2], w1a = mrow0[kt * 2 + 1];
        const u32 w0b = mrow1[kt * 2], w1b = mrow1[kt * 2 + 1];

        // --- S^T = K * Q^T
        f32x4 S[2][4];
#pragma unroll
        for (int s = 0; s < 2; ++s)
#pragma unroll
            for (int tj = 0; tj < 4; ++tj) S[s][tj] = (f32x4){0.f, 0.f, 0.f, 0.f};
#pragma unroll
        for (int tj = 0; tj < 4; ++tj) {
            const _Float16* kr = &K_lds[cb][(tj * 16 + l16) * 64];
            const int c0 = (quad ^ xr) * 8;
            half8 k0 = *(const half8*)(kr + c0);
            half8 k1 = *(const half8*)(kr + (c0 ^ 32));
            S[0][tj] = __builtin_amdgcn_mfma_f32_16x16x32_f16(k0, qf[0][0], S[0][tj], 0, 0, 0);
            S[0][tj] = __builtin_amdgcn_mfma_f32_16x16x32_f16(k1, qf[0][1], S[0][tj], 0, 0, 0);
            S[1][tj] = __builtin_amdgcn_mfma_f32_16x16x32_f16(k0, qf[1][0], S[1][tj], 0, 0, 0);
            S[1][tj] = __builtin_amdgcn_mfma_f32_16x16x32_f16(k1, qf[1][1], S[1][tj], 0, 0, 0);
        }

        // --- masked exp2 (mask pre-combined, scale pre-folded) + P write
#pragma unroll
        for (int s = 0; s < 2; ++s) {
            const u32 pw0 = s ? w0b : w0a, pw1 = s ? w1b : w1a;
#pragma unroll
            for (int tj = 0; tj < 4; ++tj) {
                const u32 m4 = ((tj & 2) ? pw1 : pw0) >> ((tj & 1) * 16 + quad * 4);
                float p[4];
#pragma unroll
                for (int reg = 0; reg < 4; ++reg) {
                    const float e = ((m4 >> reg) & 1u) ? S[s][tj][reg] : F2;
                    p[reg] = __builtin_amdgcn_exp2f(e);
                }
                lsum[s] += (p[0] + p[1]) + (p[2] + p[3]);
                half4v hp = {(_Float16)p[0], (_Float16)p[1], (_Float16)p[2], (_Float16)p[3]};
                *(half4v*)(&P_lds[(wave * 32 + s * 16 + l16) * PP + tj * 16 + quad * 4]) = hp;
            }
        }

        // --- O += P * V  (P region wave-private: no barrier)
        half8 pf0[2], pf1[2];
#pragma unroll
        for (int t = 0; t < 2; ++t) {
            pf0[t] = *(const half8*)(&P_lds[(wave * 32 + l16) * PP + t * 32 + quad * 8]);
            pf1[t] = *(const half8*)(&P_lds[(wave * 32 + 16 + l16) * PP + t * 32 + quad * 8]);
        }
#pragma unroll
        for (int t = 0; t < 2; ++t) {
            const int c0 = ((t * 4 + quad) ^ xr) * 8;
#pragma unroll
            for (int dt = 0; dt < 4; ++dt) {
                half8 vf = *(const half8*)(&V_lds[cb][(dt * 16 + l16) * 64 + c0]);
                Ov[0][dt] = __builtin_amdgcn_mfma_f32_16x16x32_f16(pf0[t], vf, Ov[0][dt], 0, 0, 0);
                Ov[1][dt] = __builtin_amdgcn_mfma_f32_16x16x32_f16(pf1[t], vf, Ov[1][dt], 0, 0, 0);
            }
        }
    }

    // --- epilogue
#pragma unroll
    for (int s = 0; s < 2; ++s) {
        lsum[s] += __shfl_xor(lsum[s], 16);
        lsum[s] += __shfl_xor(lsum[s], 32);
    }
#pragma unroll
    for (int s = 0; s < 2; ++s)
#pragma unroll
        for (int reg = 0; reg < 4; ++reg) {
            const float linv = 1.0f / __shfl(lsum[s], quad * 4 + reg);
            const int qrow = qbase + wave * 32 + s * 16 + quad * 4 + reg;
            _Float16* op = out_f16 + ((size_t)(n * L_SEQ + qrow)) * EMB + h * HD;
#pragma unroll
            for (int dt = 0; dt < 4; ++dt)
                op[dt * 16 + l16] = (_Float16)(Ov[s][dt][reg] * linv);
        }
}

// ---------------------------------------------------------------------------
// FC: C = A(f16) * W^T(f16) + bias. m97 structure: 128x128 tile, BK=64,
// global_load_lds width-16 staging, XOR-swizzled unpadded LDS.
// ---------------------------------------------------------------------------
__global__ __launch_bounds__(256, 3) void fc_kernel(
    const _Float16* __restrict__ A, const _Float16* __restrict__ W,
    const float* __restrict__ bias, float* __restrict__ C)
{
    __shared__ __align__(16) _Float16 As[128 * 64];
    __shared__ __align__(16) _Float16 Ws[128 * 64];

    const int tid = threadIdx.x;
    const int lane = tid & 63;
    const int wv = tid >> 6;
    const int l16 = lane & 15;
    const int quad = lane >> 4;
    const int wm = (wv >> 1) * 64, wn = (wv & 1) * 64;
    const int Mb = blockIdx.x * 128, Nb = blockIdx.y * 128;
    const int gch = (lane & 7) ^ ((lane >> 3) & 7);
    const int drow = lane >> 3;
    const int xr = l16 & 7;

    f32x4 acc[4][4];
#pragma unroll
    for (int i = 0; i < 4; ++i)
#pragma unroll
        for (int j = 0; j < 4; ++j) acc[i][j] = (f32x4){0.f, 0.f, 0.f, 0.f};

    for (int k0 = 0; k0 < EMB; k0 += 64) {
        __syncthreads();
#pragma unroll
        for (int s = 0; s < 4; ++s) {
            const int row = wv * 32 + s * 8 + drow;
            async16(A + (size_t)(Mb + row) * EMB + k0 + gch * 8, &As[(wv * 32 + s * 8) * 64]);
            async16(W + (size_t)(Nb + row) * EMB + k0 + gch * 8, &Ws[(wv * 32 + s * 8) * 64]);
        }
        __syncthreads();

#pragma unroll
        for (int t = 0; t < 2; ++t) {
            half8 af[4], bf[4];
            const int c0 = ((t * 4 + quad) ^ xr) * 8;
#pragma unroll
            for (int i = 0; i < 4; ++i) {
                af[i] = *(const half8*)(&As[(wm + i * 16 + l16) * 64 + c0]);
                bf[i] = *(const half8*)(&Ws[(wn + i * 16 + l16) * 64 + c0]);
            }
#pragma unroll
            for (int i = 0; i < 4; ++i)
#pragma unroll
                for (int j = 0; j < 4; ++j)
                    acc[i][j] = __builtin_amdgcn_mfma_f32_16x16x32_f16(af[i], bf[j], acc[i][j], 0, 0, 0);
        }
    }

#pragma unroll
    for (int i = 0; i < 4; ++i) {
        const int m = Mb + wm + i * 16 + quad * 4;
#pragma unroll
        for (int j = 0; j < 4; ++j) {
            const int jc = Nb + wn + j * 16 + l16;
            const float b = bias[jc];
#pragma unroll
            for (int reg = 0; reg < 4; ++reg)
                C[(size_t)(m + reg) * EMB + jc] = acc[i][j][reg] + b;
        }
    }
}

// ---------------------------------------------------------------------------
extern "C" void kernel_launch(void* const* d_in, const int* in_sizes, int n_in,
                              void* d_out, int out_size, void* d_ws, size_t ws_size,
                              hipStream_t stream) {
    const float* values  = (const float*)d_in[0];
    const float* keys    = (const float*)d_in[1];
    const float* queries = (const float*)d_in[2];
    const float* fc_w    = (const float*)d_in[3];
    const float* fc_b    = (const float*)d_in[4];
    const int*   amask   = (const int*)d_in[5];
    const int*   pmask   = (const int*)d_in[6];
    float* out = (float*)d_out;

    // ws: [0,16M) attn_out | [16M,18M) W f16 | [18M,+128K) abits |
    //     [18.5M,+1K) pbits | [19M,20M) cmb | [20M,36M) K16 | [36M,52M) Vt16
    char* w = (char*)d_ws;
    _Float16* attn_out = (_Float16*)w;
    _Float16* w_f16    = (_Float16*)(w + (size_t)16 * 1024 * 1024);
    u32*      abits    = (u32*)(w + (size_t)18 * 1024 * 1024);
    u32*      pbits    = (u32*)(w + (size_t)18 * 1024 * 1024 + 512 * 1024);
    u32*      cmb      = (u32*)(w + (size_t)19 * 1024 * 1024);
    _Float16* K16      = (_Float16*)(w + (size_t)20 * 1024 * 1024);
    _Float16* Vt16     = (_Float16*)(w + (size_t)36 * 1024 * 1024);

    pack_mask_kernel<<<4096, 256, 0, stream>>>(amask, abits);
    convert_w_kernel<<<1024, 256, 0, stream>>>(fc_w, w_f16);
    cvt_kv_kernel<<<dim3(16, 16, 8), 256, 0, stream>>>(keys, values, pmask, K16, Vt16, pbits);
    combine_mask_kernel<<<128, 256, 0, stream>>>(abits, pbits, cmb);
    attn_kernel<<<1024, 256, 0, stream>>>(K16, Vt16, queries, cmb, attn_out);
    fc_kernel<<<dim3(64, 8), 256, 0, stream>>>(attn_out, w_f16, fc_b, out);
}